// Round 7
// baseline (131.422 us; speedup 1.0000x reference)
//
#include <hip/hip_runtime.h>

// X = prod_{i=0}^{n-1} (I + A_i/n), left-to-right, A: [N,2,2] f32 row-major.
// R6 post-mortem: 2-kernel variants (R5/R6) couldn't beat R4; the remaining
// structure cost is dispatch boundaries, not tail work. R7: single fused
// kernel — last-finished block (device-scope ticket) runs the coalesced
// lane-per-partial tail in-place. Ticket reset via 4B hipMemsetAsync node.

struct M2 { double a, b, c, d; };  // [[a,b],[c,d]]

__device__ __forceinline__ M2 m2mul(const M2& X, const M2& Y) {
    M2 r;
    r.a = fma(X.a, Y.a, X.b * Y.c);
    r.b = fma(X.a, Y.b, X.b * Y.d);
    r.c = fma(X.c, Y.a, X.d * Y.c);
    r.d = fma(X.c, Y.b, X.d * Y.d);
    return r;
}

__device__ __forceinline__ M2 from_f4(float4 v, double inv_n) {
    M2 M;
    M.a = fma((double)v.x, inv_n, 1.0);
    M.b = (double)v.y * inv_n;
    M.c = (double)v.z * inv_n;
    M.d = fma((double)v.w, inv_n, 1.0);
    return M;
}

// Ordered wave tree combine: lower lane = earlier chunk = left operand.
__device__ __forceinline__ M2 wave_combine(M2 P) {
    #pragma unroll
    for (int off = 1; off < 64; off <<= 1) {
        M2 Q;
        Q.a = __shfl_down(P.a, off);
        Q.b = __shfl_down(P.b, off);
        Q.c = __shfl_down(P.c, off);
        Q.d = __shfl_down(P.d, off);
        P = m2mul(P, Q);
    }
    return P;
}

__device__ __forceinline__ M2 load_m2(const double* p) {
    double2 lo = *reinterpret_cast<const double2*>(p);
    double2 hi = *reinterpret_cast<const double2*>(p + 2);
    M2 Q = { lo.x, lo.y, hi.x, hi.y };
    return Q;
}

__device__ __forceinline__ void store_m2(double* p, const M2& P) {
    *reinterpret_cast<double2*>(p)     = double2{ P.a, P.b };
    *reinterpret_cast<double2*>(p + 2) = double2{ P.c, P.d };
}

#define CHUNK 5
#define P1_TPB 256
#define TILE (P1_TPB * CHUNK)          // 1280 matrices per block, 20 KB LDS
#define MAX_PASS 16                    // tail passes: covers 4096 partials

__global__ void __launch_bounds__(P1_TPB) prodchain_fused(
    const float4* __restrict__ A, int n, double* __restrict__ part,
    unsigned* __restrict__ ticket, float* __restrict__ out)
{
    // tile (20 KB) is reused by the tail as 64 M2 slots (2 KB) — phases are
    // barrier-separated.
    __shared__ alignas(16) unsigned char smem[TILE * 16];
    float4* tile = (float4*)smem;
    double* slots = (double*)smem;
    __shared__ double bl[4 * 4];
    __shared__ unsigned lastFlag;

    const int tid = threadIdx.x;
    const int blockStart = blockIdx.x * TILE;
    const double inv_n = 1.0 / (double)n;

    // ---- Phase 1: block partial ----
    float4 r[CHUNK];
    #pragma unroll
    for (int k = 0; k < CHUNK; ++k) {
        int g = blockStart + k * P1_TPB + tid;
        r[k] = (g < n) ? A[g] : make_float4(0.f, 0.f, 0.f, 0.f);
    }
    #pragma unroll
    for (int k = 0; k < CHUNK; ++k)
        tile[k * P1_TPB + tid] = r[k];
    __syncthreads();

    M2 P = {1.0, 0.0, 0.0, 1.0};
    const int base = tid * CHUNK;
    #pragma unroll
    for (int j = 0; j < CHUNK; ++j) {
        int gi = blockStart + base + j;
        if (gi < n) P = m2mul(P, from_f4(tile[base + j], inv_n));
    }

    P = wave_combine(P);

    const int w = tid >> 6;
    const int l = tid & 63;
    if (l == 0) {
        bl[4 * w + 0] = P.a;
        bl[4 * w + 1] = P.b;
        bl[4 * w + 2] = P.c;
        bl[4 * w + 3] = P.d;
    }
    __syncthreads();

    if (tid == 0) {
        M2 R = { bl[0], bl[1], bl[2], bl[3] };
        #pragma unroll
        for (int w2 = 1; w2 < 4; ++w2) {
            M2 Q = { bl[4 * w2 + 0], bl[4 * w2 + 1],
                     bl[4 * w2 + 2], bl[4 * w2 + 3] };
            R = m2mul(R, Q);
        }
        store_m2(&part[4 * blockIdx.x], R);
        __threadfence();                       // release: partial visible
        unsigned old = atomicAdd(ticket, 1u);  // device-scope
        lastFlag = (old == gridDim.x - 1) ? 1u : 0u;
    }
    __syncthreads();

    // ---- Tail: only the last-finished block; all partials now visible ----
    if (lastFlag) {
        __threadfence();                       // acquire
        const int np = gridDim.x;
        // Pass p, wave w, lane l -> partial p*256 + w*64 + l (coalesced).
        for (int p = 0; p * P1_TPB < np; ++p) {
            int idx = p * P1_TPB + w * 64 + l;
            M2 T = {1.0, 0.0, 0.0, 1.0};
            if (idx < np) T = load_m2(&part[4 * idx]);
            T = wave_combine(T);
            if (l == 0) {
                int s = p * 4 + w;             // global order = slot order
                slots[4 * s + 0] = T.a;
                slots[4 * s + 1] = T.b;
                slots[4 * s + 2] = T.c;
                slots[4 * s + 3] = T.d;
            }
        }
        __syncthreads();

        if (w == 0) {
            // 64 slots (some identity if np < MAX_PASS*256), ordered.
            M2 T = { slots[4 * l + 0], slots[4 * l + 1],
                     slots[4 * l + 2], slots[4 * l + 3] };
            T = wave_combine(T);
            if (l == 0) {
                out[0] = (float)T.a;
                out[1] = (float)T.b;
                out[2] = (float)T.c;
                out[3] = (float)T.d;
            }
        }
    }
}

extern "C" void kernel_launch(void* const* d_in, const int* in_sizes, int n_in,
                              void* d_out, int out_size, void* d_ws, size_t ws_size,
                              hipStream_t stream) {
    const float4* A = (const float4*)d_in[0];
    const int n = in_sizes[0] / 4;                    // 5,000,000 matrices
    const int nb1 = (n + TILE - 1) / TILE;            // 3907 blocks/partials

    double* part = (double*)d_ws;                     // 3907 * 32 B = 125 KB
    unsigned* ticket = (unsigned*)((char*)d_ws + (128 << 10));

    // Slots beyond np stay identity because the tail guards idx < np and
    // wave_combine of identities is identity; but slots for p*4+w with
    // p*256 >= np are never written -> initialize by writing identities:
    // handled in-kernel since every pass writes its slot (loop bound covers
    // all p with p*256 < np; remaining slots must be identity). Memset-free:
    // the final wave reads 64 slots, so clear unused ones via the same loop
    // bound — we instead round passes up so every slot is written.
    // (loop: p*256 < np -> 16 passes for np=3907 -> all 64 slots written.)

    hipMemsetAsync(ticket, 0, sizeof(unsigned), stream);
    prodchain_fused<<<nb1, P1_TPB, 0, stream>>>(A, n, part, ticket,
                                                (float*)d_out);
}

// Round 8
// 73.987 us; speedup vs baseline: 1.7763x; 1.7763x over previous
//
#include <hip/hip_runtime.h>

// X = prod_{i=0}^{n-1} (I + A_i/n), left-to-right, A: [N,2,2] f32 row-major.
// R7 post-mortem: __threadfence() (agent fence) = L2 writeback/inv per block
// on multi-XCD gfx950 -> chip-wide stall (160us, 223 GB/s). R8: same fused
// last-block-done structure, but FENCE-FREE coherence: partials stored with
// agent-scope relaxed atomic stores (sc1, write-through to LLC), vmcnt(0)
// drain, relaxed agent ticket; tail reads partials with agent-scope relaxed
// loads. No buffer_wbl2 anywhere. Phase-1 body identical to R4 (23.6us best).

struct M2 { double a, b, c, d; };  // [[a,b],[c,d]]

__device__ __forceinline__ M2 m2mul(const M2& X, const M2& Y) {
    M2 r;
    r.a = fma(X.a, Y.a, X.b * Y.c);
    r.b = fma(X.a, Y.b, X.b * Y.d);
    r.c = fma(X.c, Y.a, X.d * Y.c);
    r.d = fma(X.c, Y.b, X.d * Y.d);
    return r;
}

__device__ __forceinline__ M2 from_f4(float4 v, double inv_n) {
    M2 M;
    M.a = fma((double)v.x, inv_n, 1.0);
    M.b = (double)v.y * inv_n;
    M.c = (double)v.z * inv_n;
    M.d = fma((double)v.w, inv_n, 1.0);
    return M;
}

// Ordered wave tree combine: lower lane = earlier chunk = left operand.
__device__ __forceinline__ M2 wave_combine(M2 P) {
    #pragma unroll
    for (int off = 1; off < 64; off <<= 1) {
        M2 Q;
        Q.a = __shfl_down(P.a, off);
        Q.b = __shfl_down(P.b, off);
        Q.c = __shfl_down(P.c, off);
        Q.d = __shfl_down(P.d, off);
        P = m2mul(P, Q);
    }
    return P;
}

#define CHUNK 5
#define P1_TPB 256
#define TILE (P1_TPB * CHUNK)          // 1280 matrices per block, 20 KB LDS

__global__ void __launch_bounds__(P1_TPB) prodchain_fused(
    const float4* __restrict__ A, int n, double* __restrict__ part,
    unsigned* __restrict__ ticket, float* __restrict__ out)
{
    // tile (20 KB) reused by the tail as 64 ordered M2 slots (2 KB);
    // phases are barrier-separated.
    __shared__ alignas(16) unsigned char smem[TILE * 16];
    float4* tile = (float4*)smem;
    double* slots = (double*)smem;
    __shared__ double bl[4 * 4];
    __shared__ unsigned lastFlag;

    const int tid = threadIdx.x;
    const int w = tid >> 6;
    const int l = tid & 63;
    const int blockStart = blockIdx.x * TILE;
    const double inv_n = 1.0 / (double)n;

    // ---- Phase 1: block partial (identical to R4) ----
    float4 r[CHUNK];
    #pragma unroll
    for (int k = 0; k < CHUNK; ++k) {
        int g = blockStart + k * P1_TPB + tid;
        r[k] = (g < n) ? A[g] : make_float4(0.f, 0.f, 0.f, 0.f);
    }
    #pragma unroll
    for (int k = 0; k < CHUNK; ++k)
        tile[k * P1_TPB + tid] = r[k];
    __syncthreads();

    M2 P = {1.0, 0.0, 0.0, 1.0};
    const int base = tid * CHUNK;
    #pragma unroll
    for (int j = 0; j < CHUNK; ++j) {
        int gi = blockStart + base + j;
        if (gi < n) P = m2mul(P, from_f4(tile[base + j], inv_n));
    }

    P = wave_combine(P);

    if (l == 0) {
        bl[4 * w + 0] = P.a;
        bl[4 * w + 1] = P.b;
        bl[4 * w + 2] = P.c;
        bl[4 * w + 3] = P.d;
    }
    __syncthreads();

    if (tid == 0) {
        M2 R = { bl[0], bl[1], bl[2], bl[3] };
        #pragma unroll
        for (int w2 = 1; w2 < 4; ++w2) {
            M2 Q = { bl[4 * w2 + 0], bl[4 * w2 + 1],
                     bl[4 * w2 + 2], bl[4 * w2 + 3] };
            R = m2mul(R, Q);
        }
        // Coherent (sc1) write-through stores: visible device-wide via LLC,
        // no fence needed.
        double* p = &part[4 * blockIdx.x];
        __hip_atomic_store(p + 0, R.a, __ATOMIC_RELAXED, __HIP_MEMORY_SCOPE_AGENT);
        __hip_atomic_store(p + 1, R.b, __ATOMIC_RELAXED, __HIP_MEMORY_SCOPE_AGENT);
        __hip_atomic_store(p + 2, R.c, __ATOMIC_RELAXED, __HIP_MEMORY_SCOPE_AGENT);
        __hip_atomic_store(p + 3, R.d, __ATOMIC_RELAXED, __HIP_MEMORY_SCOPE_AGENT);
        asm volatile("s_waitcnt vmcnt(0)" ::: "memory");   // order stores < ticket
        unsigned old = __hip_atomic_fetch_add(ticket, 1u, __ATOMIC_RELAXED,
                                              __HIP_MEMORY_SCOPE_AGENT);
        lastFlag = (old == gridDim.x - 1) ? 1u : 0u;
    }
    __syncthreads();

    // ---- Tail: last-finished block only; partials authoritative in LLC ----
    if (lastFlag) {
        const int np = gridDim.x;
        // Pass p2, wave w, lane l -> partial p2*256 + w*64 + l (coalesced).
        for (int p2 = 0; p2 * P1_TPB < np; ++p2) {
            int idx = p2 * P1_TPB + w * 64 + l;
            M2 T = {1.0, 0.0, 0.0, 1.0};
            if (idx < np) {
                const double* q = &part[4 * idx];
                T.a = __hip_atomic_load(q + 0, __ATOMIC_RELAXED, __HIP_MEMORY_SCOPE_AGENT);
                T.b = __hip_atomic_load(q + 1, __ATOMIC_RELAXED, __HIP_MEMORY_SCOPE_AGENT);
                T.c = __hip_atomic_load(q + 2, __ATOMIC_RELAXED, __HIP_MEMORY_SCOPE_AGENT);
                T.d = __hip_atomic_load(q + 3, __ATOMIC_RELAXED, __HIP_MEMORY_SCOPE_AGENT);
            }
            T = wave_combine(T);
            if (l == 0) {
                int s = p2 * 4 + w;            // global order = slot order
                slots[4 * s + 0] = T.a;
                slots[4 * s + 1] = T.b;
                slots[4 * s + 2] = T.c;
                slots[4 * s + 3] = T.d;
            }
        }
        __syncthreads();

        if (w == 0) {
            // 16 passes x 4 waves = all 64 slots written (np=3907); ordered.
            M2 T = { slots[4 * l + 0], slots[4 * l + 1],
                     slots[4 * l + 2], slots[4 * l + 3] };
            T = wave_combine(T);
            if (l == 0) {
                out[0] = (float)T.a;
                out[1] = (float)T.b;
                out[2] = (float)T.c;
                out[3] = (float)T.d;
            }
        }
    }
}

extern "C" void kernel_launch(void* const* d_in, const int* in_sizes, int n_in,
                              void* d_out, int out_size, void* d_ws, size_t ws_size,
                              hipStream_t stream) {
    const float4* A = (const float4*)d_in[0];
    const int n = in_sizes[0] / 4;                    // 5,000,000 matrices
    const int nb1 = (n + TILE - 1) / TILE;            // 3907 blocks/partials

    double* part = (double*)d_ws;                     // 3907 * 32 B = 125 KB
    unsigned* ticket = (unsigned*)((char*)d_ws + (128 << 10));

    hipMemsetAsync(ticket, 0, sizeof(unsigned), stream);
    prodchain_fused<<<nb1, P1_TPB, 0, stream>>>(A, n, part, ticket,
                                                (float*)d_out);
}

// Round 9
// 28.560 us; speedup vs baseline: 4.6015x; 2.5905x over previous
//
#include <hip/hip_runtime.h>

// X = prod_{i=0}^{n-1} (I + A_i/n), left-to-right, A: [N,2,2] f32 row-major.
// R8 post-mortem: fused single-kernel w/ global ticket serializes 3907
// agent atomics on one LLC line (~50us) — fusion abandoned. R9: back to the
// R4 structure with (a) 512-thread blocks (TILE=2560, 40KB LDS, 4 blocks/CU,
// half the per-block combine overhead), and (b) since nb=1954 <= 2048, the
// tail is ONE 1024-thread kernel doing exactly 2 coalesced lane-per-partial
// passes. 2 dispatches total; no atomics, no fences.

struct M2 { double a, b, c, d; };  // [[a,b],[c,d]]

__device__ __forceinline__ M2 m2mul(const M2& X, const M2& Y) {
    M2 r;
    r.a = fma(X.a, Y.a, X.b * Y.c);
    r.b = fma(X.a, Y.b, X.b * Y.d);
    r.c = fma(X.c, Y.a, X.d * Y.c);
    r.d = fma(X.c, Y.b, X.d * Y.d);
    return r;
}

__device__ __forceinline__ M2 from_f4(float4 v, double inv_n) {
    M2 M;
    M.a = fma((double)v.x, inv_n, 1.0);
    M.b = (double)v.y * inv_n;
    M.c = (double)v.z * inv_n;
    M.d = fma((double)v.w, inv_n, 1.0);
    return M;
}

// Ordered wave tree combine: lower lane = earlier chunk = left operand.
// Lanes holding identity are harmless pads.
__device__ __forceinline__ M2 wave_combine(M2 P) {
    #pragma unroll
    for (int off = 1; off < 64; off <<= 1) {
        M2 Q;
        Q.a = __shfl_down(P.a, off);
        Q.b = __shfl_down(P.b, off);
        Q.c = __shfl_down(P.c, off);
        Q.d = __shfl_down(P.d, off);
        P = m2mul(P, Q);
    }
    return P;
}

__device__ __forceinline__ M2 load_m2(const double* p) {
    double2 lo = *reinterpret_cast<const double2*>(p);
    double2 hi = *reinterpret_cast<const double2*>(p + 2);
    M2 Q = { lo.x, lo.y, hi.x, hi.y };
    return Q;
}

__device__ __forceinline__ void store_m2(double* p, const M2& P) {
    *reinterpret_cast<double2*>(p)     = double2{ P.a, P.b };
    *reinterpret_cast<double2*>(p + 2) = double2{ P.c, P.d };
}

#define CHUNK 5
#define P1_TPB 512
#define P1_WAVES (P1_TPB / 64)         // 8
#define TILE (P1_TPB * CHUNK)          // 2560 matrices, 40 KB LDS -> 4 blk/CU

__global__ void __launch_bounds__(P1_TPB) prodchain_phase1(
    const float4* __restrict__ A, int n, double* __restrict__ part)
{
    __shared__ float4 tile[TILE];      // exactly 40 KB; bl[] aliases it
    double* bl = (double*)tile;        // 8 wave partials (256 B), after sync

    const int tid = threadIdx.x;
    const int w = tid >> 6;
    const int l = tid & 63;
    const int blockStart = blockIdx.x * TILE;
    const double inv_n = 1.0 / (double)n;

    // Coalesced stage: granule k*512+tid; consecutive lanes 16B apart.
    float4 r[CHUNK];
    #pragma unroll
    for (int k = 0; k < CHUNK; ++k) {
        int g = blockStart + k * P1_TPB + tid;
        r[k] = (g < n) ? A[g] : make_float4(0.f, 0.f, 0.f, 0.f);
    }
    #pragma unroll
    for (int k = 0; k < CHUNK; ++k)
        tile[k * P1_TPB + tid] = r[k];
    __syncthreads();

    // Contiguous per-thread chunk from LDS. Lane stride 80 B: start bank
    // cluster (20l mod 32) is a permutation over 8 lanes -> conflict-free.
    M2 P = {1.0, 0.0, 0.0, 1.0};
    const int base = tid * CHUNK;
    #pragma unroll
    for (int j = 0; j < CHUNK; ++j) {
        int gi = blockStart + base + j;
        if (gi < n) P = m2mul(P, from_f4(tile[base + j], inv_n));
    }

    P = wave_combine(P);

    __syncthreads();                   // all tile reads done before aliasing
    if (l == 0) {
        bl[4 * w + 0] = P.a;
        bl[4 * w + 1] = P.b;
        bl[4 * w + 2] = P.c;
        bl[4 * w + 3] = P.d;
    }
    __syncthreads();

    if (w == 0) {
        M2 T = {1.0, 0.0, 0.0, 1.0};
        if (l < P1_WAVES) T = load_m2(&bl[4 * l]);
        T = wave_combine(T);           // lanes >=8 are identity pads
        if (l == 0) store_m2(&part[4 * blockIdx.x], T);
    }
}

#define PT_TPB 1024
#define PT_WAVES (PT_TPB / 64)         // 16
#define PT_PASSES 2                    // covers up to 2048 partials

// Single block, fully coalesced ordered tail (np <= 2048). Pass p, wave w,
// lane l loads partial p*1024 + w*64 + l (identity if OOB) -> wave tree ->
// LDS slot p*16+w (global order = slot order) -> wave 0 tree -> out.
__global__ void __launch_bounds__(PT_TPB) prodchain_tail(
    const double* __restrict__ part, int np, float* __restrict__ out)
{
    __shared__ double slots[4 * PT_WAVES * PT_PASSES];   // 32 ordered slots
    const int t = threadIdx.x;
    const int l = t & 63;
    const int w = t >> 6;

    #pragma unroll
    for (int p = 0; p < PT_PASSES; ++p) {
        int idx = p * PT_TPB + t;
        M2 P = {1.0, 0.0, 0.0, 1.0};
        if (idx < np) P = load_m2(&part[4 * idx]);
        P = wave_combine(P);
        if (l == 0) {
            int s = p * PT_WAVES + w;
            slots[4 * s + 0] = P.a;
            slots[4 * s + 1] = P.b;
            slots[4 * s + 2] = P.c;
            slots[4 * s + 3] = P.d;
        }
    }
    __syncthreads();

    if (w == 0) {
        M2 P = {1.0, 0.0, 0.0, 1.0};
        if (l < PT_WAVES * PT_PASSES) P = load_m2(&slots[4 * l]);
        P = wave_combine(P);           // lanes >=32 identity pads
        if (l == 0) {
            out[0] = (float)P.a;
            out[1] = (float)P.b;
            out[2] = (float)P.c;
            out[3] = (float)P.d;
        }
    }
}

extern "C" void kernel_launch(void* const* d_in, const int* in_sizes, int n_in,
                              void* d_out, int out_size, void* d_ws, size_t ws_size,
                              hipStream_t stream) {
    const float4* A = (const float4*)d_in[0];
    const int n = in_sizes[0] / 4;                    // 5,000,000 matrices
    const int nb1 = (n + TILE - 1) / TILE;            // 1954 block partials

    double* part = (double*)d_ws;                     // 1954 * 32 B = 62.5 KB

    prodchain_phase1<<<nb1, P1_TPB, 0, stream>>>(A, n, part);
    prodchain_tail<<<1, PT_TPB, 0, stream>>>(part, nb1, (float*)d_out);
}

// Round 10
// 23.183 us; speedup vs baseline: 5.6688x; 1.2319x over previous
//
#include <hip/hip_runtime.h>

// X = prod_{i=0}^{n-1} (I + A_i/n), left-to-right, A: [N,2,2] f32 row-major.
// R9 post-mortem: all 2-dispatch variants lose to R4's 3-dispatch (23.6us).
// R10: keep R4 structure; rebuild phase1 BARRIER-FREE: each wave stages its
// OWN 320-matrix segment via global_load_lds (direct HBM->LDS, no VGPR round
// trip, wave-uniform dest + lane*16B), so no __syncthreads before consume.
// Last block uses a guarded register path (OOB -> identity factors).

struct M2 { double a, b, c, d; };  // [[a,b],[c,d]]

__device__ __forceinline__ M2 m2mul(const M2& X, const M2& Y) {
    M2 r;
    r.a = fma(X.a, Y.a, X.b * Y.c);
    r.b = fma(X.a, Y.b, X.b * Y.d);
    r.c = fma(X.c, Y.a, X.d * Y.c);
    r.d = fma(X.c, Y.b, X.d * Y.d);
    return r;
}

__device__ __forceinline__ M2 from_f4(float4 v, double inv_n) {
    M2 M;
    M.a = fma((double)v.x, inv_n, 1.0);
    M.b = (double)v.y * inv_n;
    M.c = (double)v.z * inv_n;
    M.d = fma((double)v.w, inv_n, 1.0);
    return M;
}

// Ordered wave tree combine: lower lane = earlier chunk = left operand.
__device__ __forceinline__ M2 wave_combine(M2 P) {
    #pragma unroll
    for (int off = 1; off < 64; off <<= 1) {
        M2 Q;
        Q.a = __shfl_down(P.a, off);
        Q.b = __shfl_down(P.b, off);
        Q.c = __shfl_down(P.c, off);
        Q.d = __shfl_down(P.d, off);
        P = m2mul(P, Q);
    }
    return P;
}

__device__ __forceinline__ M2 load_m2(const double* p) {
    double2 lo = *reinterpret_cast<const double2*>(p);
    double2 hi = *reinterpret_cast<const double2*>(p + 2);
    M2 Q = { lo.x, lo.y, hi.x, hi.y };
    return Q;
}

__device__ __forceinline__ void store_m2(double* p, const M2& P) {
    *reinterpret_cast<double2*>(p)     = double2{ P.a, P.b };
    *reinterpret_cast<double2*>(p + 2) = double2{ P.c, P.d };
}

#define CHUNK 5
#define P1_TPB 256
#define WTILE (64 * CHUNK)             // 320 matrices per wave
#define TILE (P1_TPB * CHUNK)          // 1280 matrices per block, 20 KB LDS

__global__ void __launch_bounds__(P1_TPB) prodchain_phase1(
    const float4* __restrict__ A, int n, double* __restrict__ part)
{
    __shared__ float4 tile[TILE];
    __shared__ double bl[4 * 4];
    const int tid = threadIdx.x;
    const int w = tid >> 6;
    const int l = tid & 63;
    const int blockStart = blockIdx.x * TILE;
    const int waveStart = blockStart + w * WTILE;   // this wave's 320 matrices
    const double inv_n = 1.0 / (double)n;

    float4* lbase = &tile[w * WTILE];               // wave-local LDS segment

    if (blockStart + TILE <= n) {
        // Fast path: direct HBM->LDS, wave-local, NO block barrier.
        // Dest = wave-uniform base + lane*16B (HW pattern); src per-lane.
        const float4* gbase = A + waveStart;
        #pragma unroll
        for (int k = 0; k < CHUNK; ++k) {
            __builtin_amdgcn_global_load_lds(
                (const __attribute__((address_space(1))) void*)(gbase + k * 64 + l),
                (__attribute__((address_space(3))) void*)(lbase + k * 64),
                16, 0, 0);
        }
        asm volatile("s_waitcnt vmcnt(0)" ::: "memory");
    } else {
        // Guarded tail block: register staging into the same wave-local
        // segment; OOB -> 0 -> identity factor (I + 0/n).
        #pragma unroll
        for (int k = 0; k < CHUNK; ++k) {
            int g = waveStart + k * 64 + l;
            float4 v = (g < n) ? A[g] : make_float4(0.f, 0.f, 0.f, 0.f);
            lbase[k * 64 + l] = v;
        }
        // ds_write -> ds_read same wave: compiler inserts lgkmcnt wait.
    }

    // Consume this wave's contiguous per-thread chunk from LDS (no barrier:
    // the segment was staged by this wave). Lane stride 80 B, conflict-free.
    M2 P = {1.0, 0.0, 0.0, 1.0};
    const float4* my = &lbase[l * CHUNK];
    #pragma unroll
    for (int j = 0; j < CHUNK; ++j)
        P = m2mul(P, from_f4(my[j], inv_n));

    P = wave_combine(P);

    if (l == 0) {
        bl[4 * w + 0] = P.a;
        bl[4 * w + 1] = P.b;
        bl[4 * w + 2] = P.c;
        bl[4 * w + 3] = P.d;
    }
    __syncthreads();                    // the ONLY block-wide barrier

    if (tid == 0) {
        M2 R = { bl[0], bl[1], bl[2], bl[3] };
        #pragma unroll
        for (int w2 = 1; w2 < 4; ++w2) {
            M2 Q = { bl[4 * w2 + 0], bl[4 * w2 + 1],
                     bl[4 * w2 + 2], bl[4 * w2 + 3] };
            R = m2mul(R, Q);
        }
        store_m2(&part[4 * blockIdx.x], R);
    }
}

// Lane-per-partial ordered reduce: block b combines partials [b*64, b*64+64)
// (identity for OOB) into out_part[b]. Coalesced 32B records.
__global__ void __launch_bounds__(64) prodchain_reduce(
    const double* __restrict__ in_part, int np, double* __restrict__ out_part)
{
    const int l = threadIdx.x;
    const int idx = blockIdx.x * 64 + l;
    M2 P = {1.0, 0.0, 0.0, 1.0};
    if (idx < np) P = load_m2(&in_part[4 * idx]);

    P = wave_combine(P);

    if (l == 0) store_m2(&out_part[4 * blockIdx.x], P);
}

__global__ void __launch_bounds__(64) prodchain_final(
    const double* __restrict__ in_part, int np, float* __restrict__ out)
{
    const int l = threadIdx.x;
    M2 P = {1.0, 0.0, 0.0, 1.0};
    if (l < np) P = load_m2(&in_part[4 * l]);

    P = wave_combine(P);

    if (l == 0) {
        out[0] = (float)P.a;
        out[1] = (float)P.b;
        out[2] = (float)P.c;
        out[3] = (float)P.d;
    }
}

extern "C" void kernel_launch(void* const* d_in, const int* in_sizes, int n_in,
                              void* d_out, int out_size, void* d_ws, size_t ws_size,
                              hipStream_t stream) {
    const float4* A = (const float4*)d_in[0];
    const int n = in_sizes[0] / 4;                    // 5,000,000 matrices
    const int nb1 = (n + TILE - 1) / TILE;            // 3907 block partials
    const int nb2 = (nb1 + 63) / 64;                  // 62 level-2 partials

    double* part1 = (double*)d_ws;                    // 3907 * 32 B = 125 KB
    double* part2 = part1 + 4 * 4096;                 // offset 128 KB

    prodchain_phase1<<<nb1, P1_TPB, 0, stream>>>(A, n, part1);
    prodchain_reduce<<<nb2, 64, 0, stream>>>(part1, nb1, part2);
    prodchain_final<<<1, 64, 0, stream>>>(part2, nb2, (float*)d_out);
}